// Round 3
// baseline (892.647 us; speedup 1.0000x reference)
//
#include <hip/hip_runtime.h>

#define BB 128
#define NN 512
#define DD 128
#define CACHE_F 13312  // floats of LDS K-cache per block (52 KB)

// ---------------- kernel 1: h -> normalized hn ----------------
__global__ __launch_bounds__(256) void hn_kernel(const float* __restrict__ h,
                                                 const float* __restrict__ W0,
                                                 const float* __restrict__ W1,
                                                 float* __restrict__ hn) {
    int wave = (int)((blockIdx.x * blockDim.x + threadIdx.x) >> 6);  // 0..B*N-1
    int lane = threadIdx.x & 63;
    const float2* h2 = (const float2*)(h + (size_t)wave * DD);
    float2 w0 = ((const float2*)W0)[lane];
    float2 w1 = ((const float2*)W1)[lane];
    float2 x = h2[lane];
    float p0 = fmaxf(x.x * w0.x, 0.0f) * w1.x;
    float p1 = fmaxf(x.y * w0.y, 0.0f) * w1.y;
    float ss = p0 * p0 + p1 * p1;
#pragma unroll
    for (int m = 32; m; m >>= 1) ss += __shfl_xor(ss, m);
    float inv = 1.0f / (sqrtf(ss) + 1e-12f);
    float2 o;
    o.x = p0 * inv;
    o.y = p1 * inv;
    ((float2*)(hn + (size_t)wave * DD))[lane] = o;
}

// ---------------- kernel 2: K = exp(2*(hn hn^T + eye) - 2) on valid region -
#define KC 32
__global__ __launch_bounds__(256) void sim_kernel(const float* __restrict__ hn,
                                                  const int* __restrict__ lengths,
                                                  float* __restrict__ K) {
    int b = blockIdx.z;
    int len = max(lengths[b], 1);
    int r0 = blockIdx.y * 128, c0 = blockIdx.x * 128;
    if (r0 >= len || c0 >= len) return;
    __shared__ float As[KC][132];
    __shared__ float Bs[KC][132];
    const float* base = hn + (size_t)b * NN * DD;
    int tid = threadIdx.x;
    int lr = tid >> 3;
    int lk = (tid & 7) << 2;
    int tx = tid & 15, ty = tid >> 4;
    float acc[8][8] = {};

    for (int kc = 0; kc < DD; kc += KC) {
#pragma unroll
        for (int rr = 0; rr < 128; rr += 32) {
            float4 a = *(const float4*)(base + (size_t)(r0 + lr + rr) * DD + kc + lk);
            As[lk + 0][lr + rr] = a.x; As[lk + 1][lr + rr] = a.y;
            As[lk + 2][lr + rr] = a.z; As[lk + 3][lr + rr] = a.w;
            float4 bb = *(const float4*)(base + (size_t)(c0 + lr + rr) * DD + kc + lk);
            Bs[lk + 0][lr + rr] = bb.x; Bs[lk + 1][lr + rr] = bb.y;
            Bs[lk + 2][lr + rr] = bb.z; Bs[lk + 3][lr + rr] = bb.w;
        }
        __syncthreads();
#pragma unroll
        for (int kk = 0; kk < KC; kk++) {
            float4 a0 = *(const float4*)&As[kk][ty * 8];
            float4 a1 = *(const float4*)&As[kk][ty * 8 + 4];
            float4 b0 = *(const float4*)&Bs[kk][tx * 4];
            float4 b1 = *(const float4*)&Bs[kk][64 + tx * 4];
            float ar[8] = {a0.x, a0.y, a0.z, a0.w, a1.x, a1.y, a1.z, a1.w};
            float bc[8] = {b0.x, b0.y, b0.z, b0.w, b1.x, b1.y, b1.z, b1.w};
#pragma unroll
            for (int r = 0; r < 8; r++)
#pragma unroll
                for (int c = 0; c < 8; c++)
                    acc[r][c] = fmaf(ar[r], bc[c], acc[r][c]);
        }
        __syncthreads();
    }
    float* out = K + (size_t)b * NN * NN;
#pragma unroll
    for (int r = 0; r < 8; r++) {
        int i = r0 + ty * 8 + r;
        if (i >= len) continue;
#pragma unroll
        for (int cg = 0; cg < 2; cg++) {
            int j0 = c0 + cg * 64 + tx * 4;
            if (j0 >= len) continue;
            float vv[4];
#pragma unroll
            for (int c = 0; c < 4; c++) {
                float s = acc[r][cg * 4 + c] + ((i == j0 + c) ? 1.0f : 0.0f);
                vv[c] = expf(2.0f * s - 2.0f);
            }
            float4 o;
            o.x = vv[0]; o.y = vv[1]; o.z = vv[2]; o.w = vv[3];
            *(float4*)(out + (size_t)i * NN + j0) = o;
        }
    }
}

// ---------------- init: zero the per-batch barrier counters ----------------
__global__ __launch_bounds__(128) void init_bars(int* __restrict__ bars) {
    bars[threadIdx.x] = 0;
}

// ---------------- persistent Sinkhorn: 20 iters, 1 pass over K per iter ----
// grid 512 x 256 (2 blocks/CU via coop launch). Block (b,q) owns row-quarter
// [q*rpq, min((q+1)*rpq,len)). One pass per iter gives both u (row dot) and
// this block's contribution to every column sum (no symmetry assumed).
// Cross-block: double-buffered per-(b,q) slots + 4-arrival atomic barrier.
__global__ __launch_bounds__(256) void coop_sink(const float* __restrict__ K,
                                                 float* __restrict__ u_buf,
                                                 float* __restrict__ v_buf,
                                                 const int* __restrict__ lengths,
                                                 int* __restrict__ bars,
                                                 float* __restrict__ slots) {
    __shared__ float cache[CACHE_F];  // 52 KB K-row cache
    __shared__ float xb[NN];          // current multiplier vector (v)
    __shared__ float pv[4 * NN];      // per-wave column partial staging

    int g = blockIdx.x;
    int b = g >> 2, q = g & 3;
    int len = max(lengths[b], 1);
    int len4 = (len + 3) & ~3;
    int rpq = (len + 3) >> 2;
    int r_lo = q * rpq;
    int nrows = min(len - r_lo, rpq);
    if (nrows < 0) nrows = 0;
    int ncache = min(nrows, CACHE_F / len4);
    float inv_n = 1.0f / (float)len;

    int tid = threadIdx.x;
    int w = tid >> 6, l = tid & 63;
    int c0 = 4 * l, c1 = 256 + 4 * l;
    bool a0 = c0 < len4, a1 = c1 < len4;
    const float* Kb = K + (size_t)b * NN * NN;
    int* bar = bars + b;

    // phase -1: stage cached rows into LDS; build xb = mf
    for (int i = w; i < ncache; i += 4) {
        const float* gp = Kb + (size_t)(r_lo + i) * NN;
        float* cp = cache + i * len4;
        for (int c = c0; c < len4; c += 256)
            *(float4*)(cp + c) = *(const float4*)(gp + c);
    }
    {
        int c = 2 * tid;
        xb[c] = (c < len) ? 1.0f : 0.0f;
        xb[c + 1] = (c + 1 < len) ? 1.0f : 0.0f;
    }
    __syncthreads();

    for (int t = 0; t < 20; t++) {
        // lane's slice of the multiplier vector (8 regs, no per-row LDS reads)
        float4 xv0 = *(const float4*)(xb + c0);
        float4 xv1 = *(const float4*)(xb + c1);
        float4 pa = {0, 0, 0, 0}, pb = {0, 0, 0, 0};

        // phase A: one pass over owned rows -> u_r and column partials
        for (int i = w; i < nrows; i += 4) {
            int r = r_lo + i;
            float4 k0 = {0, 0, 0, 0}, k1 = {0, 0, 0, 0};
            if (i < ncache) {
                const float* cp = cache + i * len4;
                if (a0) k0 = *(const float4*)(cp + c0);
                if (a1) k1 = *(const float4*)(cp + c1);
            } else {
                const float* gp = Kb + (size_t)r * NN;
                if (a0) k0 = *(const float4*)(gp + c0);
                if (a1) k1 = *(const float4*)(gp + c1);
            }
            float d = fmaf(k0.x, xv0.x, fmaf(k0.y, xv0.y, fmaf(k0.z, xv0.z, k0.w * xv0.w)));
            d = fmaf(k1.x, xv1.x, fmaf(k1.y, xv1.y, fmaf(k1.z, xv1.z, fmaf(k1.w, xv1.w, d))));
#pragma unroll
            for (int m = 32; m; m >>= 1) d += __shfl_xor(d, m);
            float uu = inv_n / (d + 1e-9f);
            pa.x = fmaf(k0.x, uu, pa.x); pa.y = fmaf(k0.y, uu, pa.y);
            pa.z = fmaf(k0.z, uu, pa.z); pa.w = fmaf(k0.w, uu, pa.w);
            pb.x = fmaf(k1.x, uu, pb.x); pb.y = fmaf(k1.y, uu, pb.y);
            pb.z = fmaf(k1.z, uu, pb.z); pb.w = fmaf(k1.w, uu, pb.w);
            if (t == 19 && l == 0) u_buf[(size_t)b * NN + r] = uu;
        }

        // phase B: reduce 4 waves' partials, publish to this block's slot
        __syncthreads();  // xb reads done; pv free to overwrite
        *(float4*)(pv + w * NN + c0) = pa;
        *(float4*)(pv + w * NN + c1) = pb;
        __syncthreads();
        float* slotp = slots + (((size_t)(t & 1) * BB * 4) + b * 4 + q) * NN;
        {
            int c = 2 * tid;
            float s0 = pv[c] + pv[NN + c] + pv[2 * NN + c] + pv[3 * NN + c];
            float s1 = pv[c + 1] + pv[NN + c + 1] + pv[2 * NN + c + 1] + pv[3 * NN + c + 1];
            float2 st; st.x = s0; st.y = s1;
            *(float2*)(slotp + c) = st;
        }

        // batch barrier: 4 arrivals (release), spin (acquire)
        __syncthreads();
        if (tid == 0) {
            __hip_atomic_fetch_add(bar, 1, __ATOMIC_RELEASE, __HIP_MEMORY_SCOPE_AGENT);
            int target = 4 * (t + 1);
            while (__hip_atomic_load(bar, __ATOMIC_ACQUIRE, __HIP_MEMORY_SCOPE_AGENT) < target)
                __builtin_amdgcn_s_sleep(2);
        }
        __syncthreads();

        // phase C: v_c = mu/(colsum+eps); rebuild xb (or final v_buf write)
        const float* sb = slots + ((size_t)(t & 1) * BB * 4 + b * 4) * NN;
#pragma unroll
        for (int k = 0; k < 2; k++) {
            int c = 2 * tid + k;
            float s = __hip_atomic_load(sb + c, __ATOMIC_RELAXED, __HIP_MEMORY_SCOPE_AGENT) +
                      __hip_atomic_load(sb + NN + c, __ATOMIC_RELAXED, __HIP_MEMORY_SCOPE_AGENT) +
                      __hip_atomic_load(sb + 2 * NN + c, __ATOMIC_RELAXED, __HIP_MEMORY_SCOPE_AGENT) +
                      __hip_atomic_load(sb + 3 * NN + c, __ATOMIC_RELAXED, __HIP_MEMORY_SCOPE_AGENT);
            float vv = (c < len) ? (inv_n / (s + 1e-9f)) : 0.0f;
            if (t < 19) {
                xb[c] = vv;
            } else if (c >= r_lo && c < r_lo + nrows) {
                v_buf[(size_t)b * NN + c] = vv;  // owner writes final v
            }
        }
        __syncthreads();
    }
}

// ---------------- kernel 4: fused epilogue, in-place on d_out -------------
__global__ __launch_bounds__(256) void epi_kernel(float* __restrict__ io,
                                                  const float* __restrict__ u,
                                                  const float* __restrict__ v,
                                                  const int* __restrict__ lengths) {
    const float E5 = 0.006737946999085467f;  // exp(-5)
    size_t idx = (size_t)blockIdx.x * 256 + threadIdx.x;  // float4 index
    int b = (int)(idx >> 16);
    int r = (int)(idx >> 7) & (NN - 1);
    int c4 = ((int)idx & 127) << 2;
    int len = max(lengths[b], 1);
    float4 o;
    if (r >= len || c4 >= len) {
        o.x = E5; o.y = E5; o.z = E5; o.w = E5;
        ((float4*)io)[idx] = o;
        return;
    }
    float4 k = ((float4*)io)[idx];
    float ui = u[(size_t)b * NN + r];
    float4 vv = *(const float4*)(v + (size_t)b * NN + c4);
    float t = (float)len * ui;
    float kv[4] = {k.x, k.y, k.z, k.w};
    float vj[4] = {vv.x, vv.y, vv.z, vv.w};
    float ov[4];
#pragma unroll
    for (int c = 0; c < 4; c++) {
        float Kc = kv[c];
        float P = t * Kc * vj[c];
        bool valid = (c4 + c) < len;
        if (valid && P > 0.1f) {
            float x = 2.5f * logf(Kc);  // == 5*sim - 5
            ov[c] = (x > 0.0f) ? (x + 1.0f) : expf(x);
        } else {
            ov[c] = E5;
        }
    }
    o.x = ov[0]; o.y = ov[1]; o.z = ov[2]; o.w = ov[3];
    ((float4*)io)[idx] = o;
}

extern "C" void kernel_launch(void* const* d_in, const int* in_sizes, int n_in,
                              void* d_out, int out_size, void* d_ws, size_t ws_size,
                              hipStream_t stream) {
    const float* h = (const float*)d_in[0];
    const float* W0 = (const float*)d_in[1];
    const float* W1 = (const float*)d_in[2];
    const int* lengths = (const int*)d_in[3];
    float* K = (float*)d_out;  // [B,N,N] K, overwritten in place by epilogue

    char* ws = (char*)d_ws;
    float* hn = (float*)ws;                                   // 33.5 MB
    size_t off = (size_t)BB * NN * DD * 4;
    float* u = (float*)(ws + off);            off += (size_t)BB * NN * 4;   // 256 KB
    float* v = (float*)(ws + off);            off += (size_t)BB * NN * 4;   // 256 KB
    float* slots = (float*)(ws + off);        off += (size_t)2 * BB * 4 * NN * 4;  // 2 MB
    int* bars = (int*)(ws + off);

    init_bars<<<1, 128, 0, stream>>>(bars);
    hn_kernel<<<BB * NN / 4, 256, 0, stream>>>(h, W0, W1, hn);
    sim_kernel<<<dim3(NN / 128, NN / 128, BB), 256, 0, stream>>>(hn, lengths, K);

    void* args[6];
    const float* Kc = K;
    args[0] = (void*)&Kc;
    args[1] = (void*)&u;
    args[2] = (void*)&v;
    args[3] = (void*)&lengths;
    args[4] = (void*)&bars;
    args[5] = (void*)&slots;
    hipLaunchCooperativeKernel((const void*)coop_sink, dim3(BB * 4), dim3(256), args, 0, stream);

    epi_kernel<<<(unsigned)((size_t)BB * NN * NN / 4 / 256), 256, 0, stream>>>(K, u, v, lengths);
}

// Round 4
// 736.329 us; speedup vs baseline: 1.2123x; 1.2123x over previous
//
#include <hip/hip_runtime.h>

#define BB 128
#define NN 512
#define DD 128
#define CACHE_F 13312  // floats of LDS K-cache per block (52 KB)

// ---------------- kernel 1: h -> normalized hn ----------------
__global__ __launch_bounds__(256) void hn_kernel(const float* __restrict__ h,
                                                 const float* __restrict__ W0,
                                                 const float* __restrict__ W1,
                                                 float* __restrict__ hn) {
    int wave = (int)((blockIdx.x * blockDim.x + threadIdx.x) >> 6);  // 0..B*N-1
    int lane = threadIdx.x & 63;
    const float2* h2 = (const float2*)(h + (size_t)wave * DD);
    float2 w0 = ((const float2*)W0)[lane];
    float2 w1 = ((const float2*)W1)[lane];
    float2 x = h2[lane];
    float p0 = fmaxf(x.x * w0.x, 0.0f) * w1.x;
    float p1 = fmaxf(x.y * w0.y, 0.0f) * w1.y;
    float ss = p0 * p0 + p1 * p1;
#pragma unroll
    for (int m = 32; m; m >>= 1) ss += __shfl_xor(ss, m);
    float inv = 1.0f / (sqrtf(ss) + 1e-12f);
    float2 o;
    o.x = p0 * inv;
    o.y = p1 * inv;
    ((float2*)(hn + (size_t)wave * DD))[lane] = o;
}

// ---------------- kernel 2: K = exp(2*(hn hn^T + eye) - 2) on valid region -
#define KC 32
__global__ __launch_bounds__(256) void sim_kernel(const float* __restrict__ hn,
                                                  const int* __restrict__ lengths,
                                                  float* __restrict__ K) {
    int b = blockIdx.z;
    int len = max(lengths[b], 1);
    int r0 = blockIdx.y * 128, c0 = blockIdx.x * 128;
    if (r0 >= len || c0 >= len) return;
    __shared__ float As[KC][132];
    __shared__ float Bs[KC][132];
    const float* base = hn + (size_t)b * NN * DD;
    int tid = threadIdx.x;
    int lr = tid >> 3;
    int lk = (tid & 7) << 2;
    int tx = tid & 15, ty = tid >> 4;
    float acc[8][8] = {};

    for (int kc = 0; kc < DD; kc += KC) {
#pragma unroll
        for (int rr = 0; rr < 128; rr += 32) {
            float4 a = *(const float4*)(base + (size_t)(r0 + lr + rr) * DD + kc + lk);
            As[lk + 0][lr + rr] = a.x; As[lk + 1][lr + rr] = a.y;
            As[lk + 2][lr + rr] = a.z; As[lk + 3][lr + rr] = a.w;
            float4 bb = *(const float4*)(base + (size_t)(c0 + lr + rr) * DD + kc + lk);
            Bs[lk + 0][lr + rr] = bb.x; Bs[lk + 1][lr + rr] = bb.y;
            Bs[lk + 2][lr + rr] = bb.z; Bs[lk + 3][lr + rr] = bb.w;
        }
        __syncthreads();
#pragma unroll
        for (int kk = 0; kk < KC; kk++) {
            float4 a0 = *(const float4*)&As[kk][ty * 8];
            float4 a1 = *(const float4*)&As[kk][ty * 8 + 4];
            float4 b0 = *(const float4*)&Bs[kk][tx * 4];
            float4 b1 = *(const float4*)&Bs[kk][64 + tx * 4];
            float ar[8] = {a0.x, a0.y, a0.z, a0.w, a1.x, a1.y, a1.z, a1.w};
            float bc[8] = {b0.x, b0.y, b0.z, b0.w, b1.x, b1.y, b1.z, b1.w};
#pragma unroll
            for (int r = 0; r < 8; r++)
#pragma unroll
                for (int c = 0; c < 8; c++)
                    acc[r][c] = fmaf(ar[r], bc[c], acc[r][c]);
        }
        __syncthreads();
    }
    float* out = K + (size_t)b * NN * NN;
#pragma unroll
    for (int r = 0; r < 8; r++) {
        int i = r0 + ty * 8 + r;
        if (i >= len) continue;
#pragma unroll
        for (int cg = 0; cg < 2; cg++) {
            int j0 = c0 + cg * 64 + tx * 4;
            if (j0 >= len) continue;
            float vv[4];
#pragma unroll
            for (int c = 0; c < 4; c++) {
                float s = acc[r][cg * 4 + c] + ((i == j0 + c) ? 1.0f : 0.0f);
                vv[c] = expf(2.0f * s - 2.0f);
            }
            float4 o;
            o.x = vv[0]; o.y = vv[1]; o.z = vv[2]; o.w = vv[3];
            *(float4*)(out + (size_t)i * NN + j0) = o;
        }
    }
}

// ---------------- init: zero the per-batch barrier counters ----------------
__global__ __launch_bounds__(128) void init_bars(int* __restrict__ bars) {
    bars[threadIdx.x] = 0;
}

// ---------------- persistent Sinkhorn: 20 iters, 1 pass over K per iter ----
// Barrier protocol is FENCE-FREE: relaxed agent-scope atomics only (sc1
// write-through / coherent-point loads). NO acquire/release — those emit
// buffer_inv / buffer_wbl2 (whole-L2 maintenance) per poll on gfx950, which
// is what made R3 stall 31 us/iter. Ordering: slot stores drain at the
// pre-barrier vmcnt(0); arrival count implies device visibility.
__global__ __launch_bounds__(256) void coop_sink(const float* __restrict__ K,
                                                 float* __restrict__ u_buf,
                                                 float* __restrict__ v_buf,
                                                 const int* __restrict__ lengths,
                                                 int* __restrict__ bars,
                                                 float* __restrict__ slots) {
    __shared__ float cache[CACHE_F];  // 52 KB K-row cache
    __shared__ float xb[NN];          // current multiplier vector (v)
    __shared__ float pv[4 * NN];      // per-wave column partial staging

    int g = blockIdx.x;
    int b = g >> 2, q = g & 3;
    int len = max(lengths[b], 1);
    int len4 = (len + 3) & ~3;
    int rpq = (len + 3) >> 2;
    int r_lo = q * rpq;
    int nrows = min(len - r_lo, rpq);
    if (nrows < 0) nrows = 0;
    int ncache = min(nrows, CACHE_F / len4);
    float inv_n = 1.0f / (float)len;

    int tid = threadIdx.x;
    int w = tid >> 6, l = tid & 63;
    int c0 = 4 * l, c1 = 256 + 4 * l;
    bool a0 = c0 < len4, a1 = c1 < len4;
    const float* Kb = K + (size_t)b * NN * NN;
    int* bar = bars + b;

    // phase -1: stage cached rows into LDS; build xb = mf
    for (int i = w; i < ncache; i += 4) {
        const float* gp = Kb + (size_t)(r_lo + i) * NN;
        float* cp = cache + i * len4;
        for (int c = c0; c < len4; c += 256)
            *(float4*)(cp + c) = *(const float4*)(gp + c);
    }
    {
        int c = 2 * tid;
        xb[c] = (c < len) ? 1.0f : 0.0f;
        xb[c + 1] = (c + 1 < len) ? 1.0f : 0.0f;
    }
    __syncthreads();

    for (int t = 0; t < 20; t++) {
        // lane's slice of the multiplier vector (8 regs, no per-row LDS reads)
        float4 xv0 = *(const float4*)(xb + c0);
        float4 xv1 = *(const float4*)(xb + c1);
        float4 pa = {0, 0, 0, 0}, pb = {0, 0, 0, 0};

        // phase A: one pass over owned rows -> u_r and column partials
        for (int i = w; i < nrows; i += 4) {
            int r = r_lo + i;
            float4 k0 = {0, 0, 0, 0}, k1 = {0, 0, 0, 0};
            if (i < ncache) {
                const float* cp = cache + i * len4;
                if (a0) k0 = *(const float4*)(cp + c0);
                if (a1) k1 = *(const float4*)(cp + c1);
            } else {
                const float* gp = Kb + (size_t)r * NN;
                if (a0) k0 = *(const float4*)(gp + c0);
                if (a1) k1 = *(const float4*)(gp + c1);
            }
            float d = fmaf(k0.x, xv0.x, fmaf(k0.y, xv0.y, fmaf(k0.z, xv0.z, k0.w * xv0.w)));
            d = fmaf(k1.x, xv1.x, fmaf(k1.y, xv1.y, fmaf(k1.z, xv1.z, fmaf(k1.w, xv1.w, d))));
#pragma unroll
            for (int m = 32; m; m >>= 1) d += __shfl_xor(d, m);
            float uu = inv_n / (d + 1e-9f);
            pa.x = fmaf(k0.x, uu, pa.x); pa.y = fmaf(k0.y, uu, pa.y);
            pa.z = fmaf(k0.z, uu, pa.z); pa.w = fmaf(k0.w, uu, pa.w);
            pb.x = fmaf(k1.x, uu, pb.x); pb.y = fmaf(k1.y, uu, pb.y);
            pb.z = fmaf(k1.z, uu, pb.z); pb.w = fmaf(k1.w, uu, pb.w);
            if (t == 19 && l == 0) u_buf[(size_t)b * NN + r] = uu;
        }

        // phase B: reduce 4 waves' partials, publish via relaxed sc1 stores
        __syncthreads();  // xb reads done; pv free to overwrite
        *(float4*)(pv + w * NN + c0) = pa;
        *(float4*)(pv + w * NN + c1) = pb;
        __syncthreads();
        float* slotp = slots + (((size_t)(t & 1) * BB * 4) + b * 4 + q) * NN;
        {
            int c = 2 * tid;
            float s0 = pv[c] + pv[NN + c] + pv[2 * NN + c] + pv[3 * NN + c];
            float s1 = pv[c + 1] + pv[NN + c + 1] + pv[2 * NN + c + 1] + pv[3 * NN + c + 1];
            __hip_atomic_store(slotp + c, s0, __ATOMIC_RELAXED, __HIP_MEMORY_SCOPE_AGENT);
            __hip_atomic_store(slotp + c + 1, s1, __ATOMIC_RELAXED, __HIP_MEMORY_SCOPE_AGENT);
        }

        // batch barrier: drain own stores, then relaxed arrive + relaxed spin
        asm volatile("s_waitcnt vmcnt(0)" ::: "memory");
        __syncthreads();  // compiler also drains every thread's vmcnt here
        if (tid == 0) {
            __hip_atomic_fetch_add(bar, 1, __ATOMIC_RELAXED, __HIP_MEMORY_SCOPE_AGENT);
            int target = 4 * (t + 1);
            while (__hip_atomic_load(bar, __ATOMIC_RELAXED, __HIP_MEMORY_SCOPE_AGENT) < target)
                __builtin_amdgcn_s_sleep(2);
        }
        __syncthreads();

        // phase C: v_c = mu/(colsum+eps); rebuild xb (or final v_buf write)
        const float* sb = slots + ((size_t)(t & 1) * BB * 4 + b * 4) * NN;
#pragma unroll
        for (int k = 0; k < 2; k++) {
            int c = 2 * tid + k;
            float s = __hip_atomic_load(sb + c, __ATOMIC_RELAXED, __HIP_MEMORY_SCOPE_AGENT) +
                      __hip_atomic_load(sb + NN + c, __ATOMIC_RELAXED, __HIP_MEMORY_SCOPE_AGENT) +
                      __hip_atomic_load(sb + 2 * NN + c, __ATOMIC_RELAXED, __HIP_MEMORY_SCOPE_AGENT) +
                      __hip_atomic_load(sb + 3 * NN + c, __ATOMIC_RELAXED, __HIP_MEMORY_SCOPE_AGENT);
            float vv = (c < len) ? (inv_n / (s + 1e-9f)) : 0.0f;
            if (t < 19) {
                xb[c] = vv;
            } else if (c >= r_lo && c < r_lo + nrows) {
                v_buf[(size_t)b * NN + c] = vv;  // owner writes final v
            }
        }
        __syncthreads();
    }
}

// ---------------- kernel 4: fused epilogue, in-place on d_out -------------
__global__ __launch_bounds__(256) void epi_kernel(float* __restrict__ io,
                                                  const float* __restrict__ u,
                                                  const float* __restrict__ v,
                                                  const int* __restrict__ lengths) {
    const float E5 = 0.006737946999085467f;  // exp(-5)
    size_t idx = (size_t)blockIdx.x * 256 + threadIdx.x;  // float4 index
    int b = (int)(idx >> 16);
    int r = (int)(idx >> 7) & (NN - 1);
    int c4 = ((int)idx & 127) << 2;
    int len = max(lengths[b], 1);
    float4 o;
    if (r >= len || c4 >= len) {
        o.x = E5; o.y = E5; o.z = E5; o.w = E5;
        ((float4*)io)[idx] = o;
        return;
    }
    float4 k = ((float4*)io)[idx];
    float ui = u[(size_t)b * NN + r];
    float4 vv = *(const float4*)(v + (size_t)b * NN + c4);
    float t = (float)len * ui;
    float kv[4] = {k.x, k.y, k.z, k.w};
    float vj[4] = {vv.x, vv.y, vv.z, vv.w};
    float ov[4];
#pragma unroll
    for (int c = 0; c < 4; c++) {
        float Kc = kv[c];
        float P = t * Kc * vj[c];
        bool valid = (c4 + c) < len;
        if (valid && P > 0.1f) {
            float x = 2.5f * logf(Kc);  // == 5*sim - 5
            ov[c] = (x > 0.0f) ? (x + 1.0f) : expf(x);
        } else {
            ov[c] = E5;
        }
    }
    o.x = ov[0]; o.y = ov[1]; o.z = ov[2]; o.w = ov[3];
    ((float4*)io)[idx] = o;
}

extern "C" void kernel_launch(void* const* d_in, const int* in_sizes, int n_in,
                              void* d_out, int out_size, void* d_ws, size_t ws_size,
                              hipStream_t stream) {
    const float* h = (const float*)d_in[0];
    const float* W0 = (const float*)d_in[1];
    const float* W1 = (const float*)d_in[2];
    const int* lengths = (const int*)d_in[3];
    float* K = (float*)d_out;  // [B,N,N] K, overwritten in place by epilogue

    char* ws = (char*)d_ws;
    float* hn = (float*)ws;                                   // 33.5 MB
    size_t off = (size_t)BB * NN * DD * 4;
    float* u = (float*)(ws + off);            off += (size_t)BB * NN * 4;   // 256 KB
    float* v = (float*)(ws + off);            off += (size_t)BB * NN * 4;   // 256 KB
    float* slots = (float*)(ws + off);        off += (size_t)2 * BB * 4 * NN * 4;  // 2 MB
    int* bars = (int*)(ws + off);

    init_bars<<<1, 128, 0, stream>>>(bars);
    hn_kernel<<<BB * NN / 4, 256, 0, stream>>>(h, W0, W1, hn);
    sim_kernel<<<dim3(NN / 128, NN / 128, BB), 256, 0, stream>>>(hn, lengths, K);

    void* args[6];
    const float* Kc = K;
    args[0] = (void*)&Kc;
    args[1] = (void*)&u;
    args[2] = (void*)&v;
    args[3] = (void*)&lengths;
    args[4] = (void*)&bars;
    args[5] = (void*)&slots;
    hipLaunchCooperativeKernel((const void*)coop_sink, dim3(BB * 4), dim3(256), args, 0, stream);

    epi_kernel<<<(unsigned)((size_t)BB * NN * NN / 4 / 256), 256, 0, stream>>>(K, u, v, lengths);
}

// Round 5
// 514.995 us; speedup vs baseline: 1.7333x; 1.4298x over previous
//
#include <hip/hip_runtime.h>

#define BB 128
#define NN 512
#define DD 128
#define SLOT_STRIDE 544  // 512 data floats + tag int at [512] + pad (2176 B, 16B-aligned)

// ---------------- kernel 1: h -> normalized hn ----------------
__global__ __launch_bounds__(256) void hn_kernel(const float* __restrict__ h,
                                                 const float* __restrict__ W0,
                                                 const float* __restrict__ W1,
                                                 float* __restrict__ hn) {
    int wave = (int)((blockIdx.x * blockDim.x + threadIdx.x) >> 6);  // 0..B*N-1
    int lane = threadIdx.x & 63;
    const float2* h2 = (const float2*)(h + (size_t)wave * DD);
    float2 w0 = ((const float2*)W0)[lane];
    float2 w1 = ((const float2*)W1)[lane];
    float2 x = h2[lane];
    float p0 = fmaxf(x.x * w0.x, 0.0f) * w1.x;
    float p1 = fmaxf(x.y * w0.y, 0.0f) * w1.y;
    float ss = p0 * p0 + p1 * p1;
#pragma unroll
    for (int m = 32; m; m >>= 1) ss += __shfl_xor(ss, m);
    float inv = 1.0f / (sqrtf(ss) + 1e-12f);
    float2 o;
    o.x = p0 * inv;
    o.y = p1 * inv;
    ((float2*)(hn + (size_t)wave * DD))[lane] = o;
}

// ---------------- kernel 2: K = exp(2*(hn hn^T + eye) - 2) on valid region -
#define KC 32
__global__ __launch_bounds__(256) void sim_kernel(const float* __restrict__ hn,
                                                  const int* __restrict__ lengths,
                                                  float* __restrict__ K) {
    int b = blockIdx.z;
    int len = max(lengths[b], 1);
    int r0 = blockIdx.y * 128, c0 = blockIdx.x * 128;
    if (r0 >= len || c0 >= len) return;
    __shared__ float As[KC][132];
    __shared__ float Bs[KC][132];
    const float* base = hn + (size_t)b * NN * DD;
    int tid = threadIdx.x;
    int lr = tid >> 3;
    int lk = (tid & 7) << 2;
    int tx = tid & 15, ty = tid >> 4;
    float acc[8][8] = {};

    for (int kc = 0; kc < DD; kc += KC) {
#pragma unroll
        for (int rr = 0; rr < 128; rr += 32) {
            float4 a = *(const float4*)(base + (size_t)(r0 + lr + rr) * DD + kc + lk);
            As[lk + 0][lr + rr] = a.x; As[lk + 1][lr + rr] = a.y;
            As[lk + 2][lr + rr] = a.z; As[lk + 3][lr + rr] = a.w;
            float4 bb = *(const float4*)(base + (size_t)(c0 + lr + rr) * DD + kc + lk);
            Bs[lk + 0][lr + rr] = bb.x; Bs[lk + 1][lr + rr] = bb.y;
            Bs[lk + 2][lr + rr] = bb.z; Bs[lk + 3][lr + rr] = bb.w;
        }
        __syncthreads();
#pragma unroll
        for (int kk = 0; kk < KC; kk++) {
            float4 a0 = *(const float4*)&As[kk][ty * 8];
            float4 a1 = *(const float4*)&As[kk][ty * 8 + 4];
            float4 b0 = *(const float4*)&Bs[kk][tx * 4];
            float4 b1 = *(const float4*)&Bs[kk][64 + tx * 4];
            float ar[8] = {a0.x, a0.y, a0.z, a0.w, a1.x, a1.y, a1.z, a1.w};
            float bc[8] = {b0.x, b0.y, b0.z, b0.w, b1.x, b1.y, b1.z, b1.w};
#pragma unroll
            for (int r = 0; r < 8; r++)
#pragma unroll
                for (int c = 0; c < 8; c++)
                    acc[r][c] = fmaf(ar[r], bc[c], acc[r][c]);
        }
        __syncthreads();
    }
    float* out = K + (size_t)b * NN * NN;
#pragma unroll
    for (int r = 0; r < 8; r++) {
        int i = r0 + ty * 8 + r;
        if (i >= len) continue;
#pragma unroll
        for (int cg = 0; cg < 2; cg++) {
            int j0 = c0 + cg * 64 + tx * 4;
            if (j0 >= len) continue;
            float vv[4];
#pragma unroll
            for (int c = 0; c < 4; c++) {
                float s = acc[r][cg * 4 + c] + ((i == j0 + c) ? 1.0f : 0.0f);
                vv[c] = expf(2.0f * s - 2.0f);
            }
            float4 o;
            o.x = vv[0]; o.y = vv[1]; o.z = vv[2]; o.w = vv[3];
            *(float4*)(out + (size_t)i * NN + j0) = o;
        }
    }
}

__device__ __forceinline__ float dot8(float4 A, float4 B, float4 x0, float4 x1) {
    float d = fmaf(A.x, x0.x, fmaf(A.y, x0.y, fmaf(A.z, x0.z, A.w * x0.w)));
    return fmaf(B.x, x1.x, fmaf(B.y, x1.y, fmaf(B.z, x1.z, fmaf(B.w, x1.w, d))));
}

// ---------------- persistent Sinkhorn: 20 iters, 1 pass over K per iter ----
// Block (b,q) owns row-quarter q of batch b. Cross-block exchange via
// double-buffered slots; readiness via per-slot TAG words (2176 B apart —
// no shared-line RMW serialization, which was R4's residual stall). All
// cross-block atomics relaxed agent scope (no L2-maintenance ops).
// Phase A is 4-row-grouped: 8 loads in flight, interleaved shuffle trees.
__global__ __launch_bounds__(256) void coop_sink(const float* __restrict__ K,
                                                 float* __restrict__ u_buf,
                                                 float* __restrict__ v_buf,
                                                 const int* __restrict__ lengths,
                                                 float* __restrict__ slots) {
    __shared__ float xb[NN];      // current multiplier vector (v)
    __shared__ float pv[4 * NN];  // per-wave column partial staging

    int g = blockIdx.x;
    int b = g >> 2, q = g & 3;
    int len = max(lengths[b], 1);
    int len4 = (len + 3) & ~3;
    int rpq = (len + 3) >> 2;
    int r_lo = q * rpq;
    int nrows = min(len - r_lo, rpq);
    if (nrows < 0) nrows = 0;
    float inv_n = 1.0f / (float)len;

    int tid = threadIdx.x;
    int w = tid >> 6, l = tid & 63;
    int c0 = 4 * l, c1 = 256 + 4 * l;
    bool a0 = c0 < len4, a1 = c1 < len4;
    const float* Kb = K + (size_t)b * NN * NN;

    {
        int c = 2 * tid;
        xb[c] = (c < len) ? 1.0f : 0.0f;
        xb[c + 1] = (c + 1 < len) ? 1.0f : 0.0f;
    }
    __syncthreads();

    for (int t = 0; t < 20; t++) {
        float4 xv0 = *(const float4*)(xb + c0);
        float4 xv1 = *(const float4*)(xb + c1);
        float4 pa = {0, 0, 0, 0}, pb = {0, 0, 0, 0};

        // ---- phase A: one pass over owned rows (4-row groups, pipelined) ----
        int i = w;
        for (; i + 12 < nrows; i += 16) {
            const float* g0 = Kb + (size_t)(r_lo + i) * NN;
            const float* g1 = g0 + (size_t)4 * NN;
            const float* g2 = g0 + (size_t)8 * NN;
            const float* g3 = g0 + (size_t)12 * NN;
            float4 A0 = {0,0,0,0}, A1 = {0,0,0,0}, A2 = {0,0,0,0}, A3 = {0,0,0,0};
            float4 B0 = {0,0,0,0}, B1 = {0,0,0,0}, B2 = {0,0,0,0}, B3 = {0,0,0,0};
            if (a0) {
                A0 = *(const float4*)(g0 + c0); A1 = *(const float4*)(g1 + c0);
                A2 = *(const float4*)(g2 + c0); A3 = *(const float4*)(g3 + c0);
            }
            if (a1) {
                B0 = *(const float4*)(g0 + c1); B1 = *(const float4*)(g1 + c1);
                B2 = *(const float4*)(g2 + c1); B3 = *(const float4*)(g3 + c1);
            }
            float d0 = dot8(A0, B0, xv0, xv1);
            float d1 = dot8(A1, B1, xv0, xv1);
            float d2 = dot8(A2, B2, xv0, xv1);
            float d3 = dot8(A3, B3, xv0, xv1);
#pragma unroll
            for (int m = 32; m; m >>= 1) {  // 4 interleaved butterfly chains
                d0 += __shfl_xor(d0, m);
                d1 += __shfl_xor(d1, m);
                d2 += __shfl_xor(d2, m);
                d3 += __shfl_xor(d3, m);
            }
            float u0 = inv_n / (d0 + 1e-9f), u1 = inv_n / (d1 + 1e-9f);
            float u2 = inv_n / (d2 + 1e-9f), u3 = inv_n / (d3 + 1e-9f);
            pa.x = fmaf(A0.x, u0, fmaf(A1.x, u1, fmaf(A2.x, u2, fmaf(A3.x, u3, pa.x))));
            pa.y = fmaf(A0.y, u0, fmaf(A1.y, u1, fmaf(A2.y, u2, fmaf(A3.y, u3, pa.y))));
            pa.z = fmaf(A0.z, u0, fmaf(A1.z, u1, fmaf(A2.z, u2, fmaf(A3.z, u3, pa.z))));
            pa.w = fmaf(A0.w, u0, fmaf(A1.w, u1, fmaf(A2.w, u2, fmaf(A3.w, u3, pa.w))));
            pb.x = fmaf(B0.x, u0, fmaf(B1.x, u1, fmaf(B2.x, u2, fmaf(B3.x, u3, pb.x))));
            pb.y = fmaf(B0.y, u0, fmaf(B1.y, u1, fmaf(B2.y, u2, fmaf(B3.y, u3, pb.y))));
            pb.z = fmaf(B0.z, u0, fmaf(B1.z, u1, fmaf(B2.z, u2, fmaf(B3.z, u3, pb.z))));
            pb.w = fmaf(B0.w, u0, fmaf(B1.w, u1, fmaf(B2.w, u2, fmaf(B3.w, u3, pb.w))));
            if (t == 19 && l == 0) {
                float* ub = u_buf + (size_t)b * NN + r_lo;
                ub[i] = u0; ub[i + 4] = u1; ub[i + 8] = u2; ub[i + 12] = u3;
            }
        }
        for (; i < nrows; i += 4) {  // remainder rows
            const float* g0 = Kb + (size_t)(r_lo + i) * NN;
            float4 A = {0,0,0,0}, B = {0,0,0,0};
            if (a0) A = *(const float4*)(g0 + c0);
            if (a1) B = *(const float4*)(g0 + c1);
            float d = dot8(A, B, xv0, xv1);
#pragma unroll
            for (int m = 32; m; m >>= 1) d += __shfl_xor(d, m);
            float uu = inv_n / (d + 1e-9f);
            pa.x = fmaf(A.x, uu, pa.x); pa.y = fmaf(A.y, uu, pa.y);
            pa.z = fmaf(A.z, uu, pa.z); pa.w = fmaf(A.w, uu, pa.w);
            pb.x = fmaf(B.x, uu, pb.x); pb.y = fmaf(B.y, uu, pb.y);
            pb.z = fmaf(B.z, uu, pb.z); pb.w = fmaf(B.w, uu, pb.w);
            if (t == 19 && l == 0) u_buf[(size_t)b * NN + r_lo + i] = uu;
        }

        // ---- phase B: block-reduce 4 waves' partials, publish slot + tag ----
        *(float4*)(pv + w * NN + c0) = pa;
        *(float4*)(pv + w * NN + c1) = pb;
        __syncthreads();
        float* slotp = slots + ((size_t)(t & 1) * BB * 4 + (size_t)b * 4 + q) * SLOT_STRIDE;
        int c = 2 * tid;
        float s0 = pv[c] + pv[NN + c] + pv[2 * NN + c] + pv[3 * NN + c];
        float s1 = pv[c + 1] + pv[NN + c + 1] + pv[2 * NN + c + 1] + pv[3 * NN + c + 1];
        __hip_atomic_store(slotp + c, s0, __ATOMIC_RELAXED, __HIP_MEMORY_SCOPE_AGENT);
        __hip_atomic_store(slotp + c + 1, s1, __ATOMIC_RELAXED, __HIP_MEMORY_SCOPE_AGENT);
        asm volatile("s_waitcnt vmcnt(0)" ::: "memory");
        __syncthreads();  // all threads' slot stores drained before tag
        if (tid == 0)
            __hip_atomic_store((int*)(slotp + 512), t + 1, __ATOMIC_RELAXED,
                               __HIP_MEMORY_SCOPE_AGENT);
        // ---- barrier: poll the 3 sibling tags (distinct lines, loads only) --
        if (tid < 4 && tid != q) {
            const int* tagp = (const int*)(slots +
                ((size_t)(t & 1) * BB * 4 + (size_t)b * 4 + tid) * SLOT_STRIDE + 512);
            while (__hip_atomic_load(tagp, __ATOMIC_RELAXED, __HIP_MEMORY_SCOPE_AGENT) != t + 1)
                __builtin_amdgcn_s_sleep(1);
        }
        __syncthreads();

        // ---- phase C: v_c = mu/(colsum+eps); own partial stays in regs ----
        const float* sbase = slots + ((size_t)(t & 1) * BB * 4 + (size_t)b * 4) * SLOT_STRIDE;
        int q1 = (q + 1) & 3, q2 = (q + 2) & 3, q3 = (q + 3) & 3;
        float t0 = s0 +
            __hip_atomic_load(sbase + q1 * SLOT_STRIDE + c, __ATOMIC_RELAXED, __HIP_MEMORY_SCOPE_AGENT) +
            __hip_atomic_load(sbase + q2 * SLOT_STRIDE + c, __ATOMIC_RELAXED, __HIP_MEMORY_SCOPE_AGENT) +
            __hip_atomic_load(sbase + q3 * SLOT_STRIDE + c, __ATOMIC_RELAXED, __HIP_MEMORY_SCOPE_AGENT);
        float t1 = s1 +
            __hip_atomic_load(sbase + q1 * SLOT_STRIDE + c + 1, __ATOMIC_RELAXED, __HIP_MEMORY_SCOPE_AGENT) +
            __hip_atomic_load(sbase + q2 * SLOT_STRIDE + c + 1, __ATOMIC_RELAXED, __HIP_MEMORY_SCOPE_AGENT) +
            __hip_atomic_load(sbase + q3 * SLOT_STRIDE + c + 1, __ATOMIC_RELAXED, __HIP_MEMORY_SCOPE_AGENT);
        float v0 = (c < len) ? (inv_n / (t0 + 1e-9f)) : 0.0f;
        float v1 = (c + 1 < len) ? (inv_n / (t1 + 1e-9f)) : 0.0f;
        if (t < 19) {
            xb[c] = v0;
            xb[c + 1] = v1;
        } else {
            if (c >= r_lo && c < r_lo + nrows) v_buf[(size_t)b * NN + c] = v0;
            if (c + 1 >= r_lo && c + 1 < r_lo + nrows) v_buf[(size_t)b * NN + c + 1] = v1;
        }
        __syncthreads();
    }
}

// ---------------- kernel 4: fused epilogue, in-place on d_out -------------
__global__ __launch_bounds__(256) void epi_kernel(float* __restrict__ io,
                                                  const float* __restrict__ u,
                                                  const float* __restrict__ v,
                                                  const int* __restrict__ lengths) {
    const float E5 = 0.006737946999085467f;  // exp(-5)
    size_t idx = (size_t)blockIdx.x * 256 + threadIdx.x;  // float4 index
    int b = (int)(idx >> 16);
    int r = (int)(idx >> 7) & (NN - 1);
    int c4 = ((int)idx & 127) << 2;
    int len = max(lengths[b], 1);
    float4 o;
    if (r >= len || c4 >= len) {
        o.x = E5; o.y = E5; o.z = E5; o.w = E5;
        ((float4*)io)[idx] = o;
        return;
    }
    float4 k = ((float4*)io)[idx];
    float ui = u[(size_t)b * NN + r];
    float4 vv = *(const float4*)(v + (size_t)b * NN + c4);
    float t = (float)len * ui;
    float kv[4] = {k.x, k.y, k.z, k.w};
    float vj[4] = {vv.x, vv.y, vv.z, vv.w};
    float ov[4];
#pragma unroll
    for (int c = 0; c < 4; c++) {
        float Kc = kv[c];
        float P = t * Kc * vj[c];
        bool valid = (c4 + c) < len;
        if (valid && P > 0.1f) {
            float x = 2.5f * logf(Kc);  // == 5*sim - 5
            ov[c] = (x > 0.0f) ? (x + 1.0f) : expf(x);
        } else {
            ov[c] = E5;
        }
    }
    o.x = ov[0]; o.y = ov[1]; o.z = ov[2]; o.w = ov[3];
    ((float4*)io)[idx] = o;
}

extern "C" void kernel_launch(void* const* d_in, const int* in_sizes, int n_in,
                              void* d_out, int out_size, void* d_ws, size_t ws_size,
                              hipStream_t stream) {
    const float* h = (const float*)d_in[0];
    const float* W0 = (const float*)d_in[1];
    const float* W1 = (const float*)d_in[2];
    const int* lengths = (const int*)d_in[3];
    float* K = (float*)d_out;  // [B,N,N] K, overwritten in place by epilogue

    char* ws = (char*)d_ws;
    float* hn = (float*)ws;                                   // 33.5 MB
    size_t off = (size_t)BB * NN * DD * 4;
    float* u = (float*)(ws + off);     off += (size_t)BB * NN * 4;                // 256 KB
    float* v = (float*)(ws + off);     off += (size_t)BB * NN * 4;                // 256 KB
    float* slots = (float*)(ws + off); off += (size_t)2 * BB * 4 * SLOT_STRIDE * 4;  // 2.2 MB

    hn_kernel<<<BB * NN / 4, 256, 0, stream>>>(h, W0, W1, hn);
    sim_kernel<<<dim3(NN / 128, NN / 128, BB), 256, 0, stream>>>(hn, lengths, K);

    void* args[5];
    const float* Kc = K;
    args[0] = (void*)&Kc;
    args[1] = (void*)&u;
    args[2] = (void*)&v;
    args[3] = (void*)&lengths;
    args[4] = (void*)&slots;
    hipLaunchCooperativeKernel((const void*)coop_sink, dim3(BB * 4), dim3(256), args, 0, stream);

    epi_kernel<<<(unsigned)((size_t)BB * NN * NN / 4 / 256), 256, 0, stream>>>(K, u, v, lengths);
}

// Round 9
// 478.758 us; speedup vs baseline: 1.8645x; 1.0757x over previous
//
#include <hip/hip_runtime.h>

#define BB 128
#define NN 512
#define DD 128
#define SLOT_STRIDE 544  // 512 data floats + tag int at [512] + pad (2176 B)

// ---------------- kernel 1: h -> normalized hn ----------------
__global__ __launch_bounds__(256) void hn_kernel(const float* __restrict__ h,
                                                 const float* __restrict__ W0,
                                                 const float* __restrict__ W1,
                                                 float* __restrict__ hn) {
    int wave = (int)((blockIdx.x * blockDim.x + threadIdx.x) >> 6);  // 0..B*N-1
    int lane = threadIdx.x & 63;
    const float2* h2 = (const float2*)(h + (size_t)wave * DD);
    float2 w0 = ((const float2*)W0)[lane];
    float2 w1 = ((const float2*)W1)[lane];
    float2 x = h2[lane];
    float p0 = fmaxf(x.x * w0.x, 0.0f) * w1.x;
    float p1 = fmaxf(x.y * w0.y, 0.0f) * w1.y;
    float ss = p0 * p0 + p1 * p1;
#pragma unroll
    for (int m = 32; m; m >>= 1) ss += __shfl_xor(ss, m);
    float inv = 1.0f / (sqrtf(ss) + 1e-12f);
    float2 o;
    o.x = p0 * inv;
    o.y = p1 * inv;
    ((float2*)(hn + (size_t)wave * DD))[lane] = o;
}

// ---------------- kernel 2: K = exp(2*(hn hn^T + eye) - 2), persistent -----
// Persistent GEMM over the flattened list of VALID 128x128 tiles. Per-tile
// arithmetic is IDENTICAL to the R5 early-exit version (K bitwise equal);
// only the block->tile assignment changes (fixes 13% occupancy).
#define KC 32
__global__ __launch_bounds__(256) void sim_kernel(const float* __restrict__ hn,
                                                  const int* __restrict__ lengths,
                                                  float* __restrict__ K) {
    __shared__ float As[KC][132];
    __shared__ float Bs[KC][132];
    __shared__ int pre[BB + 1];  // prefix sum of per-batch tile counts
    int tid = threadIdx.x;
    if (tid == 0) {
        int acc = 0;
        for (int b = 0; b < BB; b++) {
            pre[b] = acc;
            int len = max(lengths[b], 1);
            int nt = (len + 127) >> 7;
            acc += nt * nt;
        }
        pre[BB] = acc;
    }
    __syncthreads();
    int total = pre[BB];

    int lr = tid >> 3;
    int lk = (tid & 7) << 2;
    int tx = tid & 15, ty = tid >> 4;

    for (int t = blockIdx.x; t < total; t += gridDim.x) {
        int lo = 0, hi = BB;
        while (lo + 1 < hi) {
            int mid = (lo + hi) >> 1;
            if (pre[mid] <= t) lo = mid; else hi = mid;
        }
        int b = lo;
        int local = t - pre[b];
        int len = max(lengths[b], 1);
        int nt = (len + 127) >> 7;
        int ti = local / nt;
        int tj = local - ti * nt;
        int r0 = ti << 7, c0 = tj << 7;
        const float* base = hn + (size_t)b * NN * DD;
        float acc[8][8] = {};

        for (int kc = 0; kc < DD; kc += KC) {
#pragma unroll
            for (int rr = 0; rr < 128; rr += 32) {
                float4 a = *(const float4*)(base + (size_t)(r0 + lr + rr) * DD + kc + lk);
                As[lk + 0][lr + rr] = a.x; As[lk + 1][lr + rr] = a.y;
                As[lk + 2][lr + rr] = a.z; As[lk + 3][lr + rr] = a.w;
                float4 bb = *(const float4*)(base + (size_t)(c0 + lr + rr) * DD + kc + lk);
                Bs[lk + 0][lr + rr] = bb.x; Bs[lk + 1][lr + rr] = bb.y;
                Bs[lk + 2][lr + rr] = bb.z; Bs[lk + 3][lr + rr] = bb.w;
            }
            __syncthreads();
#pragma unroll
            for (int kk = 0; kk < KC; kk++) {
                float4 a0 = *(const float4*)&As[kk][ty * 8];
                float4 a1 = *(const float4*)&As[kk][ty * 8 + 4];
                float4 b0 = *(const float4*)&Bs[kk][tx * 4];
                float4 b1 = *(const float4*)&Bs[kk][64 + tx * 4];
                float ar[8] = {a0.x, a0.y, a0.z, a0.w, a1.x, a1.y, a1.z, a1.w};
                float bc[8] = {b0.x, b0.y, b0.z, b0.w, b1.x, b1.y, b1.z, b1.w};
#pragma unroll
                for (int r = 0; r < 8; r++)
#pragma unroll
                    for (int c = 0; c < 8; c++)
                        acc[r][c] = fmaf(ar[r], bc[c], acc[r][c]);
            }
            __syncthreads();
        }
        float* out = K + (size_t)b * NN * NN;
#pragma unroll
        for (int r = 0; r < 8; r++) {
            int i = r0 + ty * 8 + r;
            if (i >= len) continue;
#pragma unroll
            for (int cg = 0; cg < 2; cg++) {
                int j0 = c0 + cg * 64 + tx * 4;
                if (j0 >= len) continue;
                float vv[4];
#pragma unroll
                for (int c = 0; c < 4; c++) {
                    float s = acc[r][cg * 4 + c] + ((i == j0 + c) ? 1.0f : 0.0f);
                    vv[c] = expf(2.0f * s - 2.0f);
                }
                float4 o;
                o.x = vv[0]; o.y = vv[1]; o.z = vv[2]; o.w = vv[3];
                *(float4*)(out + (size_t)i * NN + j0) = o;
            }
        }
    }
}

__device__ __forceinline__ float dot8(float4 A, float4 B, float4 x0, float4 x1) {
    float d = fmaf(A.x, x0.x, fmaf(A.y, x0.y, fmaf(A.z, x0.z, A.w * x0.w)));
    return fmaf(B.x, x1.x, fmaf(B.y, x1.y, fmaf(B.z, x1.z, fmaf(B.w, x1.w, d))));
}

// ---------------- persistent Sinkhorn: 20 iters, 1 pass over K per iter ----
// BYTE-IDENTICAL to the R5 version that passed twice (launch shape 512x256,
// 4 slots/batch, same accumulation order — R6/R7/R8 all changed the
// column-partial summation order and all failed on a razor-edge diagonal
// P_ii threshold flip). Only addition: #pragma unroll 2 on the phase-A main
// loop — duplicates the body WITHOUT reassociating FP ops (bitwise-safe),
// letting the next group's 8 loads issue above this group's shuffle chain.
__global__ __launch_bounds__(256) void coop_sink(const float* __restrict__ K,
                                                 float* __restrict__ u_buf,
                                                 float* __restrict__ v_buf,
                                                 const int* __restrict__ lengths,
                                                 float* __restrict__ slots) {
    __shared__ float xb[NN];      // current multiplier vector (v)
    __shared__ float pv[4 * NN];  // per-wave column partial staging

    int g = blockIdx.x;
    int b = g >> 2, q = g & 3;
    int len = max(lengths[b], 1);
    int len4 = (len + 3) & ~3;
    int rpq = (len + 3) >> 2;
    int r_lo = q * rpq;
    int nrows = min(len - r_lo, rpq);
    if (nrows < 0) nrows = 0;
    float inv_n = 1.0f / (float)len;

    int tid = threadIdx.x;
    int w = tid >> 6, l = tid & 63;
    int c0 = 4 * l, c1 = 256 + 4 * l;
    bool a0 = c0 < len4, a1 = c1 < len4;
    const float* Kb = K + (size_t)b * NN * NN;

    {
        int c = 2 * tid;
        xb[c] = (c < len) ? 1.0f : 0.0f;
        xb[c + 1] = (c + 1 < len) ? 1.0f : 0.0f;
    }
    __syncthreads();

    for (int t = 0; t < 20; t++) {
        float4 xv0 = *(const float4*)(xb + c0);
        float4 xv1 = *(const float4*)(xb + c1);
        float4 pa = {0, 0, 0, 0}, pb = {0, 0, 0, 0};

        // ---- phase A: one pass over owned rows (4-row groups, pipelined) ----
        int i = w;
#pragma unroll 2
        for (; i + 12 < nrows; i += 16) {
            const float* g0 = Kb + (size_t)(r_lo + i) * NN;
            const float* g1 = g0 + (size_t)4 * NN;
            const float* g2 = g0 + (size_t)8 * NN;
            const float* g3 = g0 + (size_t)12 * NN;
            float4 A0 = {0,0,0,0}, A1 = {0,0,0,0}, A2 = {0,0,0,0}, A3 = {0,0,0,0};
            float4 B0 = {0,0,0,0}, B1 = {0,0,0,0}, B2 = {0,0,0,0}, B3 = {0,0,0,0};
            if (a0) {
                A0 = *(const float4*)(g0 + c0); A1 = *(const float4*)(g1 + c0);
                A2 = *(const float4*)(g2 + c0); A3 = *(const float4*)(g3 + c0);
            }
            if (a1) {
                B0 = *(const float4*)(g0 + c1); B1 = *(const float4*)(g1 + c1);
                B2 = *(const float4*)(g2 + c1); B3 = *(const float4*)(g3 + c1);
            }
            float d0 = dot8(A0, B0, xv0, xv1);
            float d1 = dot8(A1, B1, xv0, xv1);
            float d2 = dot8(A2, B2, xv0, xv1);
            float d3 = dot8(A3, B3, xv0, xv1);
#pragma unroll
            for (int m = 32; m; m >>= 1) {  // 4 interleaved butterfly chains
                d0 += __shfl_xor(d0, m);
                d1 += __shfl_xor(d1, m);
                d2 += __shfl_xor(d2, m);
                d3 += __shfl_xor(d3, m);
            }
            float u0 = inv_n / (d0 + 1e-9f), u1 = inv_n / (d1 + 1e-9f);
            float u2 = inv_n / (d2 + 1e-9f), u3 = inv_n / (d3 + 1e-9f);
            pa.x = fmaf(A0.x, u0, fmaf(A1.x, u1, fmaf(A2.x, u2, fmaf(A3.x, u3, pa.x))));
            pa.y = fmaf(A0.y, u0, fmaf(A1.y, u1, fmaf(A2.y, u2, fmaf(A3.y, u3, pa.y))));
            pa.z = fmaf(A0.z, u0, fmaf(A1.z, u1, fmaf(A2.z, u2, fmaf(A3.z, u3, pa.z))));
            pa.w = fmaf(A0.w, u0, fmaf(A1.w, u1, fmaf(A2.w, u2, fmaf(A3.w, u3, pa.w))));
            pb.x = fmaf(B0.x, u0, fmaf(B1.x, u1, fmaf(B2.x, u2, fmaf(B3.x, u3, pb.x))));
            pb.y = fmaf(B0.y, u0, fmaf(B1.y, u1, fmaf(B2.y, u2, fmaf(B3.y, u3, pb.y))));
            pb.z = fmaf(B0.z, u0, fmaf(B1.z, u1, fmaf(B2.z, u2, fmaf(B3.z, u3, pb.z))));
            pb.w = fmaf(B0.w, u0, fmaf(B1.w, u1, fmaf(B2.w, u2, fmaf(B3.w, u3, pb.w))));
            if (t == 19 && l == 0) {
                float* ub = u_buf + (size_t)b * NN + r_lo;
                ub[i] = u0; ub[i + 4] = u1; ub[i + 8] = u2; ub[i + 12] = u3;
            }
        }
        for (; i < nrows; i += 4) {  // remainder rows
            const float* g0 = Kb + (size_t)(r_lo + i) * NN;
            float4 A = {0,0,0,0}, B = {0,0,0,0};
            if (a0) A = *(const float4*)(g0 + c0);
            if (a1) B = *(const float4*)(g0 + c1);
            float d = dot8(A, B, xv0, xv1);
#pragma unroll
            for (int m = 32; m; m >>= 1) d += __shfl_xor(d, m);
            float uu = inv_n / (d + 1e-9f);
            pa.x = fmaf(A.x, uu, pa.x); pa.y = fmaf(A.y, uu, pa.y);
            pa.z = fmaf(A.z, uu, pa.z); pa.w = fmaf(A.w, uu, pa.w);
            pb.x = fmaf(B.x, uu, pb.x); pb.y = fmaf(B.y, uu, pb.y);
            pb.z = fmaf(B.z, uu, pb.z); pb.w = fmaf(B.w, uu, pb.w);
            if (t == 19 && l == 0) u_buf[(size_t)b * NN + r_lo + i] = uu;
        }

        // ---- phase B: block-reduce 4 waves' partials, publish slot + tag ----
        *(float4*)(pv + w * NN + c0) = pa;
        *(float4*)(pv + w * NN + c1) = pb;
        __syncthreads();
        float* slotp = slots + ((size_t)(t & 1) * BB * 4 + (size_t)b * 4 + q) * SLOT_STRIDE;
        int c = 2 * tid;
        float s0 = pv[c] + pv[NN + c] + pv[2 * NN + c] + pv[3 * NN + c];
        float s1 = pv[c + 1] + pv[NN + c + 1] + pv[2 * NN + c + 1] + pv[3 * NN + c + 1];
        __hip_atomic_store(slotp + c, s0, __ATOMIC_RELAXED, __HIP_MEMORY_SCOPE_AGENT);
        __hip_atomic_store(slotp + c + 1, s1, __ATOMIC_RELAXED, __HIP_MEMORY_SCOPE_AGENT);
        asm volatile("s_waitcnt vmcnt(0)" ::: "memory");
        __syncthreads();  // all threads' slot stores drained before tag
        if (tid == 0)
            __hip_atomic_store((int*)(slotp + 512), t + 1, __ATOMIC_RELAXED,
                               __HIP_MEMORY_SCOPE_AGENT);
        // ---- barrier: poll the 3 sibling tags (distinct lines, loads only) --
        if (tid < 4 && tid != q) {
            const int* tagp = (const int*)(slots +
                ((size_t)(t & 1) * BB * 4 + (size_t)b * 4 + tid) * SLOT_STRIDE + 512);
            while (__hip_atomic_load(tagp, __ATOMIC_RELAXED, __HIP_MEMORY_SCOPE_AGENT) != t + 1)
                __builtin_amdgcn_s_sleep(1);
        }
        __syncthreads();

        // ---- phase C: v_c = mu/(colsum+eps); own partial stays in regs ----
        const float* sbase = slots + ((size_t)(t & 1) * BB * 4 + (size_t)b * 4) * SLOT_STRIDE;
        int q1 = (q + 1) & 3, q2 = (q + 2) & 3, q3 = (q + 3) & 3;
        float t0 = s0 +
            __hip_atomic_load(sbase + q1 * SLOT_STRIDE + c, __ATOMIC_RELAXED, __HIP_MEMORY_SCOPE_AGENT) +
            __hip_atomic_load(sbase + q2 * SLOT_STRIDE + c, __ATOMIC_RELAXED, __HIP_MEMORY_SCOPE_AGENT) +
            __hip_atomic_load(sbase + q3 * SLOT_STRIDE + c, __ATOMIC_RELAXED, __HIP_MEMORY_SCOPE_AGENT);
        float t1 = s1 +
            __hip_atomic_load(sbase + q1 * SLOT_STRIDE + c + 1, __ATOMIC_RELAXED, __HIP_MEMORY_SCOPE_AGENT) +
            __hip_atomic_load(sbase + q2 * SLOT_STRIDE + c + 1, __ATOMIC_RELAXED, __HIP_MEMORY_SCOPE_AGENT) +
            __hip_atomic_load(sbase + q3 * SLOT_STRIDE + c + 1, __ATOMIC_RELAXED, __HIP_MEMORY_SCOPE_AGENT);
        float v0 = (c < len) ? (inv_n / (t0 + 1e-9f)) : 0.0f;
        float v1 = (c + 1 < len) ? (inv_n / (t1 + 1e-9f)) : 0.0f;
        if (t < 19) {
            xb[c] = v0;
            xb[c + 1] = v1;
        } else {
            if (c >= r_lo && c < r_lo + nrows) v_buf[(size_t)b * NN + c] = v0;
            if (c + 1 >= r_lo && c + 1 < r_lo + nrows) v_buf[(size_t)b * NN + c + 1] = v1;
        }
        __syncthreads();
    }
}

// ---------------- kernel 4: fused epilogue, in-place on d_out -------------
__global__ __launch_bounds__(256) void epi_kernel(float* __restrict__ io,
                                                  const float* __restrict__ u,
                                                  const float* __restrict__ v,
                                                  const int* __restrict__ lengths) {
    const float E5 = 0.006737946999085467f;  // exp(-5)
    size_t idx = (size_t)blockIdx.x * 256 + threadIdx.x;  // float4 index
    int b = (int)(idx >> 16);
    int r = (int)(idx >> 7) & (NN - 1);
    int c4 = ((int)idx & 127) << 2;
    int len = max(lengths[b], 1);
    float4 o;
    if (r >= len || c4 >= len) {
        o.x = E5; o.y = E5; o.z = E5; o.w = E5;
        ((float4*)io)[idx] = o;
        return;
    }
    float4 k = ((float4*)io)[idx];
    float ui = u[(size_t)b * NN + r];
    float4 vv = *(const float4*)(v + (size_t)b * NN + c4);
    float t = (float)len * ui;
    float kv[4] = {k.x, k.y, k.z, k.w};
    float vj[4] = {vv.x, vv.y, vv.z, vv.w};
    float ov[4];
#pragma unroll
    for (int c = 0; c < 4; c++) {
        float Kc = kv[c];
        float P = t * Kc * vj[c];
        bool valid = (c4 + c) < len;
        if (valid && P > 0.1f) {
            float x = 2.5f * logf(Kc);  // == 5*sim - 5
            ov[c] = (x > 0.0f) ? (x + 1.0f) : expf(x);
        } else {
            ov[c] = E5;
        }
    }
    o.x = ov[0]; o.y = ov[1]; o.z = ov[2]; o.w = ov[3];
    ((float4*)io)[idx] = o;
}

extern "C" void kernel_launch(void* const* d_in, const int* in_sizes, int n_in,
                              void* d_out, int out_size, void* d_ws, size_t ws_size,
                              hipStream_t stream) {
    const float* h = (const float*)d_in[0];
    const float* W0 = (const float*)d_in[1];
    const float* W1 = (const float*)d_in[2];
    const int* lengths = (const int*)d_in[3];
    float* K = (float*)d_out;  // [B,N,N] K, overwritten in place by epilogue

    char* ws = (char*)d_ws;
    float* hn = (float*)ws;                                   // 33.5 MB
    size_t off = (size_t)BB * NN * DD * 4;
    float* u = (float*)(ws + off);     off += (size_t)BB * NN * 4;                   // 256 KB
    float* v = (float*)(ws + off);     off += (size_t)BB * NN * 4;                   // 256 KB
    float* slots = (float*)(ws + off); off += (size_t)2 * BB * 4 * SLOT_STRIDE * 4;  // 2.2 MB

    hn_kernel<<<BB * NN / 4, 256, 0, stream>>>(h, W0, W1, hn);
    sim_kernel<<<1024, 256, 0, stream>>>(hn, lengths, K);

    void* args[5];
    const float* Kc = K;
    args[0] = (void*)&Kc;
    args[1] = (void*)&u;
    args[2] = (void*)&v;
    args[3] = (void*)&lengths;
    args[4] = (void*)&slots;
    hipLaunchCooperativeKernel((const void*)coop_sink, dim3(BB * 4), dim3(256), args, 0, stream);

    epi_kernel<<<(unsigned)((size_t)BB * NN * NN / 4 / 256), 256, 0, stream>>>(K, u, v, lengths);
}

// Round 11
// 452.753 us; speedup vs baseline: 1.9716x; 1.0574x over previous
//
#include <hip/hip_runtime.h>

#define BB 128
#define NN 512
#define DD 128
#define SLOT_STRIDE 544  // 512 data floats + tag int at [512] + pad (2176 B)

// ---------------- kernel 1: h -> normalized hn ----------------
__global__ __launch_bounds__(256) void hn_kernel(const float* __restrict__ h,
                                                 const float* __restrict__ W0,
                                                 const float* __restrict__ W1,
                                                 float* __restrict__ hn) {
    int wave = (int)((blockIdx.x * blockDim.x + threadIdx.x) >> 6);  // 0..B*N-1
    int lane = threadIdx.x & 63;
    const float2* h2 = (const float2*)(h + (size_t)wave * DD);
    float2 w0 = ((const float2*)W0)[lane];
    float2 w1 = ((const float2*)W1)[lane];
    float2 x = h2[lane];
    float p0 = fmaxf(x.x * w0.x, 0.0f) * w1.x;
    float p1 = fmaxf(x.y * w0.y, 0.0f) * w1.y;
    float ss = p0 * p0 + p1 * p1;
#pragma unroll
    for (int m = 32; m; m >>= 1) ss += __shfl_xor(ss, m);
    float inv = 1.0f / (sqrtf(ss) + 1e-12f);
    float2 o;
    o.x = p0 * inv;
    o.y = p1 * inv;
    ((float2*)(hn + (size_t)wave * DD))[lane] = o;
}

// ---------------- kernel 2: K = exp(2*(hn hn^T + eye) - 2), persistent -----
// Persistent GEMM over the flattened list of VALID 128x128 tiles (R9-proven).
#define KC 32
__global__ __launch_bounds__(256) void sim_kernel(const float* __restrict__ hn,
                                                  const int* __restrict__ lengths,
                                                  float* __restrict__ K) {
    __shared__ float As[KC][132];
    __shared__ float Bs[KC][132];
    __shared__ int pre[BB + 1];  // prefix sum of per-batch tile counts
    int tid = threadIdx.x;
    if (tid == 0) {
        int acc = 0;
        for (int b = 0; b < BB; b++) {
            pre[b] = acc;
            int len = max(lengths[b], 1);
            int nt = (len + 127) >> 7;
            acc += nt * nt;
        }
        pre[BB] = acc;
    }
    __syncthreads();
    int total = pre[BB];

    int lr = tid >> 3;
    int lk = (tid & 7) << 2;
    int tx = tid & 15, ty = tid >> 4;

    for (int t = blockIdx.x; t < total; t += gridDim.x) {
        int lo = 0, hi = BB;
        while (lo + 1 < hi) {
            int mid = (lo + hi) >> 1;
            if (pre[mid] <= t) lo = mid; else hi = mid;
        }
        int b = lo;
        int local = t - pre[b];
        int len = max(lengths[b], 1);
        int nt = (len + 127) >> 7;
        int ti = local / nt;
        int tj = local - ti * nt;
        int r0 = ti << 7, c0 = tj << 7;
        const float* base = hn + (size_t)b * NN * DD;
        float acc[8][8] = {};

        for (int kc = 0; kc < DD; kc += KC) {
#pragma unroll
            for (int rr = 0; rr < 128; rr += 32) {
                float4 a = *(const float4*)(base + (size_t)(r0 + lr + rr) * DD + kc + lk);
                As[lk + 0][lr + rr] = a.x; As[lk + 1][lr + rr] = a.y;
                As[lk + 2][lr + rr] = a.z; As[lk + 3][lr + rr] = a.w;
                float4 bb = *(const float4*)(base + (size_t)(c0 + lr + rr) * DD + kc + lk);
                Bs[lk + 0][lr + rr] = bb.x; Bs[lk + 1][lr + rr] = bb.y;
                Bs[lk + 2][lr + rr] = bb.z; Bs[lk + 3][lr + rr] = bb.w;
            }
            __syncthreads();
#pragma unroll
            for (int kk = 0; kk < KC; kk++) {
                float4 a0 = *(const float4*)&As[kk][ty * 8];
                float4 a1 = *(const float4*)&As[kk][ty * 8 + 4];
                float4 b0 = *(const float4*)&Bs[kk][tx * 4];
                float4 b1 = *(const float4*)&Bs[kk][64 + tx * 4];
                float ar[8] = {a0.x, a0.y, a0.z, a0.w, a1.x, a1.y, a1.z, a1.w};
                float bc[8] = {b0.x, b0.y, b0.z, b0.w, b1.x, b1.y, b1.z, b1.w};
#pragma unroll
                for (int r = 0; r < 8; r++)
#pragma unroll
                    for (int c = 0; c < 8; c++)
                        acc[r][c] = fmaf(ar[r], bc[c], acc[r][c]);
            }
            __syncthreads();
        }
        float* out = K + (size_t)b * NN * NN;
#pragma unroll
        for (int r = 0; r < 8; r++) {
            int i = r0 + ty * 8 + r;
            if (i >= len) continue;
#pragma unroll
            for (int cg = 0; cg < 2; cg++) {
                int j0 = c0 + cg * 64 + tx * 4;
                if (j0 >= len) continue;
                float vv[4];
#pragma unroll
                for (int c = 0; c < 4; c++) {
                    float s = acc[r][cg * 4 + c] + ((i == j0 + c) ? 1.0f : 0.0f);
                    vv[c] = expf(2.0f * s - 2.0f);
                }
                float4 o;
                o.x = vv[0]; o.y = vv[1]; o.z = vv[2]; o.w = vv[3];
                *(float4*)(out + (size_t)i * NN + j0) = o;
            }
        }
    }
}

__device__ __forceinline__ float dot8(float4 A, float4 B, float4 x0, float4 x1) {
    float d = fmaf(A.x, x0.x, fmaf(A.y, x0.y, fmaf(A.z, x0.z, A.w * x0.w)));
    return fmaf(B.x, x1.x, fmaf(B.y, x1.y, fmaf(B.z, x1.z, fmaf(B.w, x1.w, d))));
}

// ---------------- persistent Sinkhorn: 20 iters, 1 pass over K per iter ----
// BYTE-IDENTICAL kernel body to R9 (the passing binary: VGPR 48, 256 thr,
// 512 blocks). FROZEN: fmaf/butterfly/reduce order AND the resource profile
// (R6/R7/R8/R10 each changed threads/grid/VGPR of the cooperative launch and
// the coop validator silently refused to run them -> u,v stayed poison).
// R11: launched as a REGULAR kernel — we never use grid-sync APIs, our
// tag-word barrier is self-contained, and capacity (>=8 blocks/CU by
// LDS/VGPR, need 2) guarantees all 512 blocks resident. Removes both the
// silent-rejection failure mode and the coop-API launch overhead.
__global__ __launch_bounds__(256) void coop_sink(const float* __restrict__ K,
                                                 float* __restrict__ u_buf,
                                                 float* __restrict__ v_buf,
                                                 const int* __restrict__ lengths,
                                                 float* __restrict__ slots) {
    __shared__ float xb[NN];      // current multiplier vector (v)
    __shared__ float pv[4 * NN];  // per-wave column partial staging

    int g = blockIdx.x;
    int b = g >> 2, q = g & 3;
    int len = max(lengths[b], 1);
    int len4 = (len + 3) & ~3;
    int rpq = (len + 3) >> 2;
    int r_lo = q * rpq;
    int nrows = min(len - r_lo, rpq);
    if (nrows < 0) nrows = 0;
    float inv_n = 1.0f / (float)len;

    int tid = threadIdx.x;
    int w = tid >> 6, l = tid & 63;
    int c0 = 4 * l, c1 = 256 + 4 * l;
    bool a0 = c0 < len4, a1 = c1 < len4;
    const float* Kb = K + (size_t)b * NN * NN;

    {
        int c = 2 * tid;
        xb[c] = (c < len) ? 1.0f : 0.0f;
        xb[c + 1] = (c + 1 < len) ? 1.0f : 0.0f;
    }
    __syncthreads();

    for (int t = 0; t < 20; t++) {
        float4 xv0 = *(const float4*)(xb + c0);
        float4 xv1 = *(const float4*)(xb + c1);
        float4 pa = {0, 0, 0, 0}, pb = {0, 0, 0, 0};

        // ---- phase A: one pass over owned rows (4-row groups, pipelined) ----
        int i = w;
#pragma unroll 2
        for (; i + 12 < nrows; i += 16) {
            const float* g0 = Kb + (size_t)(r_lo + i) * NN;
            const float* g1 = g0 + (size_t)4 * NN;
            const float* g2 = g0 + (size_t)8 * NN;
            const float* g3 = g0 + (size_t)12 * NN;
            float4 A0 = {0,0,0,0}, A1 = {0,0,0,0}, A2 = {0,0,0,0}, A3 = {0,0,0,0};
            float4 B0 = {0,0,0,0}, B1 = {0,0,0,0}, B2 = {0,0,0,0}, B3 = {0,0,0,0};
            if (a0) {
                A0 = *(const float4*)(g0 + c0); A1 = *(const float4*)(g1 + c0);
                A2 = *(const float4*)(g2 + c0); A3 = *(const float4*)(g3 + c0);
            }
            if (a1) {
                B0 = *(const float4*)(g0 + c1); B1 = *(const float4*)(g1 + c1);
                B2 = *(const float4*)(g2 + c1); B3 = *(const float4*)(g3 + c1);
            }
            float d0 = dot8(A0, B0, xv0, xv1);
            float d1 = dot8(A1, B1, xv0, xv1);
            float d2 = dot8(A2, B2, xv0, xv1);
            float d3 = dot8(A3, B3, xv0, xv1);
#pragma unroll
            for (int m = 32; m; m >>= 1) {  // 4 interleaved butterfly chains
                d0 += __shfl_xor(d0, m);
                d1 += __shfl_xor(d1, m);
                d2 += __shfl_xor(d2, m);
                d3 += __shfl_xor(d3, m);
            }
            float u0 = inv_n / (d0 + 1e-9f), u1 = inv_n / (d1 + 1e-9f);
            float u2 = inv_n / (d2 + 1e-9f), u3 = inv_n / (d3 + 1e-9f);
            pa.x = fmaf(A0.x, u0, fmaf(A1.x, u1, fmaf(A2.x, u2, fmaf(A3.x, u3, pa.x))));
            pa.y = fmaf(A0.y, u0, fmaf(A1.y, u1, fmaf(A2.y, u2, fmaf(A3.y, u3, pa.y))));
            pa.z = fmaf(A0.z, u0, fmaf(A1.z, u1, fmaf(A2.z, u2, fmaf(A3.z, u3, pa.z))));
            pa.w = fmaf(A0.w, u0, fmaf(A1.w, u1, fmaf(A2.w, u2, fmaf(A3.w, u3, pa.w))));
            pb.x = fmaf(B0.x, u0, fmaf(B1.x, u1, fmaf(B2.x, u2, fmaf(B3.x, u3, pb.x))));
            pb.y = fmaf(B0.y, u0, fmaf(B1.y, u1, fmaf(B2.y, u2, fmaf(B3.y, u3, pb.y))));
            pb.z = fmaf(B0.z, u0, fmaf(B1.z, u1, fmaf(B2.z, u2, fmaf(B3.z, u3, pb.z))));
            pb.w = fmaf(B0.w, u0, fmaf(B1.w, u1, fmaf(B2.w, u2, fmaf(B3.w, u3, pb.w))));
            if (t == 19 && l == 0) {
                float* ub = u_buf + (size_t)b * NN + r_lo;
                ub[i] = u0; ub[i + 4] = u1; ub[i + 8] = u2; ub[i + 12] = u3;
            }
        }
        for (; i < nrows; i += 4) {  // remainder rows
            const float* g0 = Kb + (size_t)(r_lo + i) * NN;
            float4 A = {0,0,0,0}, B = {0,0,0,0};
            if (a0) A = *(const float4*)(g0 + c0);
            if (a1) B = *(const float4*)(g0 + c1);
            float d = dot8(A, B, xv0, xv1);
#pragma unroll
            for (int m = 32; m; m >>= 1) d += __shfl_xor(d, m);
            float uu = inv_n / (d + 1e-9f);
            pa.x = fmaf(A.x, uu, pa.x); pa.y = fmaf(A.y, uu, pa.y);
            pa.z = fmaf(A.z, uu, pa.z); pa.w = fmaf(A.w, uu, pa.w);
            pb.x = fmaf(B.x, uu, pb.x); pb.y = fmaf(B.y, uu, pb.y);
            pb.z = fmaf(B.z, uu, pb.z); pb.w = fmaf(B.w, uu, pb.w);
            if (t == 19 && l == 0) u_buf[(size_t)b * NN + r_lo + i] = uu;
        }

        // ---- phase B: block-reduce 4 waves' partials, publish slot + tag ----
        *(float4*)(pv + w * NN + c0) = pa;
        *(float4*)(pv + w * NN + c1) = pb;
        __syncthreads();
        float* slotp = slots + ((size_t)(t & 1) * BB * 4 + (size_t)b * 4 + q) * SLOT_STRIDE;
        int c = 2 * tid;
        float s0 = pv[c] + pv[NN + c] + pv[2 * NN + c] + pv[3 * NN + c];
        float s1 = pv[c + 1] + pv[NN + c + 1] + pv[2 * NN + c + 1] + pv[3 * NN + c + 1];
        __hip_atomic_store(slotp + c, s0, __ATOMIC_RELAXED, __HIP_MEMORY_SCOPE_AGENT);
        __hip_atomic_store(slotp + c + 1, s1, __ATOMIC_RELAXED, __HIP_MEMORY_SCOPE_AGENT);
        asm volatile("s_waitcnt vmcnt(0)" ::: "memory");
        __syncthreads();  // all threads' slot stores drained before tag
        if (tid == 0)
            __hip_atomic_store((int*)(slotp + 512), t + 1, __ATOMIC_RELAXED,
                               __HIP_MEMORY_SCOPE_AGENT);
        // ---- barrier: poll the 3 sibling tags (distinct lines, loads only) --
        if (tid < 4 && tid != q) {
            const int* tagp = (const int*)(slots +
                ((size_t)(t & 1) * BB * 4 + (size_t)b * 4 + tid) * SLOT_STRIDE + 512);
            while (__hip_atomic_load(tagp, __ATOMIC_RELAXED, __HIP_MEMORY_SCOPE_AGENT) != t + 1)
                __builtin_amdgcn_s_sleep(1);
        }
        __syncthreads();

        // ---- phase C: v_c = mu/(colsum+eps); own partial stays in regs ----
        const float* sbase = slots + ((size_t)(t & 1) * BB * 4 + (size_t)b * 4) * SLOT_STRIDE;
        int q1 = (q + 1) & 3, q2 = (q + 2) & 3, q3 = (q + 3) & 3;
        float t0 = s0 +
            __hip_atomic_load(sbase + q1 * SLOT_STRIDE + c, __ATOMIC_RELAXED, __HIP_MEMORY_SCOPE_AGENT) +
            __hip_atomic_load(sbase + q2 * SLOT_STRIDE + c, __ATOMIC_RELAXED, __HIP_MEMORY_SCOPE_AGENT) +
            __hip_atomic_load(sbase + q3 * SLOT_STRIDE + c, __ATOMIC_RELAXED, __HIP_MEMORY_SCOPE_AGENT);
        float t1 = s1 +
            __hip_atomic_load(sbase + q1 * SLOT_STRIDE + c + 1, __ATOMIC_RELAXED, __HIP_MEMORY_SCOPE_AGENT) +
            __hip_atomic_load(sbase + q2 * SLOT_STRIDE + c + 1, __ATOMIC_RELAXED, __HIP_MEMORY_SCOPE_AGENT) +
            __hip_atomic_load(sbase + q3 * SLOT_STRIDE + c + 1, __ATOMIC_RELAXED, __HIP_MEMORY_SCOPE_AGENT);
        float v0 = (c < len) ? (inv_n / (t0 + 1e-9f)) : 0.0f;
        float v1 = (c + 1 < len) ? (inv_n / (t1 + 1e-9f)) : 0.0f;
        if (t < 19) {
            xb[c] = v0;
            xb[c + 1] = v1;
        } else {
            if (c >= r_lo && c < r_lo + nrows) v_buf[(size_t)b * NN + c] = v0;
            if (c + 1 >= r_lo && c + 1 < r_lo + nrows) v_buf[(size_t)b * NN + c + 1] = v1;
        }
        __syncthreads();
    }
}

// ---------------- kernel 4: fused epilogue, in-place on d_out -------------
__global__ __launch_bounds__(256) void epi_kernel(float* __restrict__ io,
                                                  const float* __restrict__ u,
                                                  const float* __restrict__ v,
                                                  const int* __restrict__ lengths) {
    const float E5 = 0.006737946999085467f;  // exp(-5)
    size_t idx = (size_t)blockIdx.x * 256 + threadIdx.x;  // float4 index
    int b = (int)(idx >> 16);
    int r = (int)(idx >> 7) & (NN - 1);
    int c4 = ((int)idx & 127) << 2;
    int len = max(lengths[b], 1);
    float4 o;
    if (r >= len || c4 >= len) {
        o.x = E5; o.y = E5; o.z = E5; o.w = E5;
        ((float4*)io)[idx] = o;
        return;
    }
    float4 k = ((float4*)io)[idx];
    float ui = u[(size_t)b * NN + r];
    float4 vv = *(const float4*)(v + (size_t)b * NN + c4);
    float t = (float)len * ui;
    float kv[4] = {k.x, k.y, k.z, k.w};
    float vj[4] = {vv.x, vv.y, vv.z, vv.w};
    float ov[4];
#pragma unroll
    for (int c = 0; c < 4; c++) {
        float Kc = kv[c];
        float P = t * Kc * vj[c];
        bool valid = (c4 + c) < len;
        if (valid && P > 0.1f) {
            float x = 2.5f * logf(Kc);  // == 5*sim - 5
            ov[c] = (x > 0.0f) ? (x + 1.0f) : expf(x);
        } else {
            ov[c] = E5;
        }
    }
    o.x = ov[0]; o.y = ov[1]; o.z = ov[2]; o.w = ov[3];
    ((float4*)io)[idx] = o;
}

extern "C" void kernel_launch(void* const* d_in, const int* in_sizes, int n_in,
                              void* d_out, int out_size, void* d_ws, size_t ws_size,
                              hipStream_t stream) {
    const float* h = (const float*)d_in[0];
    const float* W0 = (const float*)d_in[1];
    const float* W1 = (const float*)d_in[2];
    const int* lengths = (const int*)d_in[3];
    float* K = (float*)d_out;  // [B,N,N] K, overwritten in place by epilogue

    char* ws = (char*)d_ws;
    float* hn = (float*)ws;                                   // 33.5 MB
    size_t off = (size_t)BB * NN * DD * 4;
    float* u = (float*)(ws + off);     off += (size_t)BB * NN * 4;                   // 256 KB
    float* v = (float*)(ws + off);     off += (size_t)BB * NN * 4;                   // 256 KB
    float* slots = (float*)(ws + off); off += (size_t)2 * BB * 4 * SLOT_STRIDE * 4;  // 2.2 MB

    hn_kernel<<<BB * NN / 4, 256, 0, stream>>>(h, W0, W1, hn);
    sim_kernel<<<1024, 256, 0, stream>>>(hn, lengths, K);

    // Regular launch: 512 blocks x 256 thr; capacity >= 8 blocks/CU (VGPR 48,
    // LDS 10 KB) guarantees co-residency of all 512 for the tag-word barrier.
    coop_sink<<<BB * 4, 256, 0, stream>>>(K, u, v, lengths, slots);

    epi_kernel<<<(unsigned)((size_t)BB * NN * NN / 4 / 256), 256, 0, stream>>>(K, u, v, lengths);
}